// Round 2
// baseline (461.974 us; speedup 1.0000x reference)
//
#include <hip/hip_runtime.h>

// VectorQuantizer: N=262144 rows, D=64 dims, K=512 codewords, fp32.
// out layout (floats): [0,N) idx ; [N, N+N*D) quantized_st ; [N+N*D] vq_loss
//
// CORRECTNESS MODEL: the harness's np reference computes, in float32,
//   d2 = x2 - 2.0*(x @ w.T) + w2 ;  idx = argmin(d2, axis=1)
// Rounding at magnitude |x2|~64 (ulp 7.6e-6) creates rounded TIES that the
// reference resolves toward the lower index — so we must reproduce the exact
// fp32 bit pattern of d2, not the exact math. All critical ops use
// __fmul_rn/__fadd_rn/__fmaf_rn to forbid contraction/reassociation.
#define NROWS 262144
#define DDIM  64
#define KCB   512

// numpy FLOAT_pairwise_sum order for n=64 over terms fl(a[i]*a[i]):
// 8 accumulators r[j]=t[j]; r[j]+=t[8i+j]; ((r0+r1)+(r2+r3))+((r4+r5)+(r6+r7))
__device__ __forceinline__ float np_sumsq64(const float* a) {
    float r[8];
#pragma unroll
    for (int j = 0; j < 8; ++j) r[j] = __fmul_rn(a[j], a[j]);
#pragma unroll
    for (int i = 8; i < 64; i += 8) {
#pragma unroll
        for (int j = 0; j < 8; ++j)
            r[j] = __fadd_rn(r[j], __fmul_rn(a[i + j], a[i + j]));
    }
    return __fadd_rn(__fadd_rn(__fadd_rn(r[0], r[1]), __fadd_rn(r[2], r[3])),
                     __fadd_rn(__fadd_rn(r[4], r[5]), __fadd_rn(r[6], r[7])));
}

// ---- kernel 1: w2[k] = np.sum(w[k]*w[k]) in numpy's order ----
__global__ void w2_kernel(const float* __restrict__ w, float* __restrict__ w2) {
    int k = blockIdx.x * blockDim.x + threadIdx.x;
    if (k < KCB) {
        float ws[64];
        const float4* wp = (const float4*)(w + (size_t)k * DDIM);
#pragma unroll
        for (int j = 0; j < 16; ++j) {
            float4 v = wp[j];
            ws[4 * j + 0] = v.x; ws[4 * j + 1] = v.y;
            ws[4 * j + 2] = v.z; ws[4 * j + 3] = v.w;
        }
        w2[k] = np_sumsq64(ws);
    }
}

// ---- kernel 2: per-row fp32-faithful argmin + gather + loss ----
__launch_bounds__(256)
__global__ void vq_kernel(const float* __restrict__ x,
                          const float* __restrict__ w,
                          const float* __restrict__ w2,
                          float* __restrict__ out_idx,
                          float* __restrict__ out_q,
                          float* __restrict__ out_loss) {
    const int row = blockIdx.x * blockDim.x + threadIdx.x;

    // row into registers
    float xs[64];
    {
        const float4* xp = (const float4*)(x + (size_t)row * DDIM);
#pragma unroll
        for (int j = 0; j < 16; ++j) {
            float4 v = xp[j];
            xs[4 * j + 0] = v.x; xs[4 * j + 1] = v.y;
            xs[4 * j + 2] = v.z; xs[4 * j + 3] = v.w;
        }
    }

    // x2 in numpy's exact summation order
    const float x2 = np_sumsq64(xs);

    float best = 3.4e38f;
    int bidx = 0;

    // k-loop: 4 codewords at a time (4 independent sequential-FMA chains).
    // Each chain is BLAS-order: m = fma(x_k, w_k, m), k ascending from 0.
    for (int k = 0; k < KCB; k += 4) {
        const float* w0 = w + (size_t)(k + 0) * DDIM;
        const float* w1 = w + (size_t)(k + 1) * DDIM;
        const float* w2r = w + (size_t)(k + 2) * DDIM;
        const float* w3 = w + (size_t)(k + 3) * DDIM;
        float m0 = 0.f, m1 = 0.f, m2 = 0.f, m3 = 0.f;
#pragma unroll
        for (int j = 0; j < 64; j += 4) {
            float4 b0 = *(const float4*)(w0 + j);
            float4 b1 = *(const float4*)(w1 + j);
            float4 b2 = *(const float4*)(w2r + j);
            float4 b3 = *(const float4*)(w3 + j);
            m0 = __fmaf_rn(xs[j + 0], b0.x, m0);
            m1 = __fmaf_rn(xs[j + 0], b1.x, m1);
            m2 = __fmaf_rn(xs[j + 0], b2.x, m2);
            m3 = __fmaf_rn(xs[j + 0], b3.x, m3);
            m0 = __fmaf_rn(xs[j + 1], b0.y, m0);
            m1 = __fmaf_rn(xs[j + 1], b1.y, m1);
            m2 = __fmaf_rn(xs[j + 1], b2.y, m2);
            m3 = __fmaf_rn(xs[j + 1], b3.y, m3);
            m0 = __fmaf_rn(xs[j + 2], b0.z, m0);
            m1 = __fmaf_rn(xs[j + 2], b1.z, m1);
            m2 = __fmaf_rn(xs[j + 2], b2.z, m2);
            m3 = __fmaf_rn(xs[j + 2], b3.z, m3);
            m0 = __fmaf_rn(xs[j + 3], b0.w, m0);
            m1 = __fmaf_rn(xs[j + 3], b1.w, m1);
            m2 = __fmaf_rn(xs[j + 3], b2.w, m2);
            m3 = __fmaf_rn(xs[j + 3], b3.w, m3);
        }
        // d2 = fl(fl(x2 - fl(2*m)) + w2[k])   (2*m is exact)
        float d0 = __fadd_rn(__fsub_rn(x2, __fmul_rn(2.0f, m0)), w2[k + 0]);
        float d1 = __fadd_rn(__fsub_rn(x2, __fmul_rn(2.0f, m1)), w2[k + 1]);
        float d2 = __fadd_rn(__fsub_rn(x2, __fmul_rn(2.0f, m2)), w2[k + 2]);
        float d3 = __fadd_rn(__fsub_rn(x2, __fmul_rn(2.0f, m3)), w2[k + 3]);
        // ascending-k strict < == np.argmin first-min tie-break
        if (d0 < best) { best = d0; bidx = k + 0; }
        if (d1 < best) { best = d1; bidx = k + 1; }
        if (d2 < best) { best = d2; bidx = k + 2; }
        if (d3 < best) { best = d3; bidx = k + 3; }
    }

    // gather winning codeword; quantized_st = fl(x + fl(q - x)); loss terms
    const float4* wq = (const float4*)(w + (size_t)bidx * DDIM);
    float4* qo = (float4*)(out_q + (size_t)row * DDIM);
    float ls = 0.0f;
#pragma unroll
    for (int j = 0; j < 16; ++j) {
        float4 wv = wq[j];
        float xv0 = xs[4 * j + 0], xv1 = xs[4 * j + 1];
        float xv2 = xs[4 * j + 2], xv3 = xs[4 * j + 3];
        float e0 = __fsub_rn(wv.x, xv0), e1 = __fsub_rn(wv.y, xv1);
        float e2 = __fsub_rn(wv.z, xv2), e3 = __fsub_rn(wv.w, xv3);
        ls = fmaf(e0, e0, ls); ls = fmaf(e1, e1, ls);
        ls = fmaf(e2, e2, ls); ls = fmaf(e3, e3, ls);
        float4 q;
        q.x = __fadd_rn(xv0, e0); q.y = __fadd_rn(xv1, e1);
        q.z = __fadd_rn(xv2, e2); q.w = __fadd_rn(xv3, e3);
        qo[j] = q;
    }
    out_idx[row] = (float)bidx;

    // loss: wave shuffle -> LDS across 4 waves -> 1 atomic per block
#pragma unroll
    for (int off = 32; off > 0; off >>= 1) ls += __shfl_down(ls, off);
    __shared__ float red[4];
    const int lane = threadIdx.x & 63;
    const int wid  = threadIdx.x >> 6;
    if (lane == 0) red[wid] = ls;
    __syncthreads();
    if (threadIdx.x == 0) {
        float t = (red[0] + red[1]) + (red[2] + red[3]);
        // vq_loss = (1 + BETA) * mean((q-x)^2), BETA=0.25
        atomicAdd(out_loss, t * (1.25f / (float)(NROWS * DDIM)));
    }
}

extern "C" void kernel_launch(void* const* d_in, const int* in_sizes, int n_in,
                              void* d_out, int out_size, void* d_ws, size_t ws_size,
                              hipStream_t stream) {
    const float* x = (const float*)d_in[0];   // encoding [N, 64]
    const float* w = (const float*)d_in[1];   // weight   [512, 64]

    float* out      = (float*)d_out;
    float* out_idx  = out;                                        // N floats
    float* out_q    = out + (size_t)NROWS;                        // N*D floats
    float* out_loss = out + (size_t)NROWS + (size_t)NROWS * DDIM; // 1 float

    float* w2 = (float*)d_ws;  // 512 floats scratch

    // loss slot must start at 0 (d_out is poisoned before each launch)
    hipMemsetAsync(out_loss, 0, sizeof(float), stream);

    w2_kernel<<<2, 256, 0, stream>>>(w, w2);
    vq_kernel<<<NROWS / 256, 256, 0, stream>>>(x, w, w2, out_idx, out_q, out_loss);
}

// Round 3
// 420.533 us; speedup vs baseline: 1.0985x; 1.0985x over previous
//
#include <hip/hip_runtime.h>

// VectorQuantizer: N=262144 rows, D=64 dims, K=512 codewords, fp32.
// out layout (floats): [0,N) idx ; [N, N+N*D) quantized_st ; [N+N*D] vq_loss
//
// CORRECTNESS MODEL (verified R2, absmax 0): reproduce the np reference's fp32
// bit pattern: d2 = fl(fl(x2 - fl(2*m)) + w2), x2/w2 in numpy pairwise-8 order,
// m = sequential FMA chain over k ascending (BLAS order), argmin strict <.
// All critical ops __fmul_rn/__fadd_rn/__fmaf_rn (no contraction/reassoc).
//
// R3 change: __launch_bounds__(256,2) so xs[64] stays in registers (R2 compiled
// to VGPR=48 -> xs rematerialized/spilled -> 43% of VALU issue was non-FMA).
// Also widen to 8 independent codeword chains per group.
#define NROWS 262144
#define DDIM  64
#define KCB   512

// numpy FLOAT_pairwise_sum order for n=64 over terms fl(a[i]*a[i])
__device__ __forceinline__ float np_sumsq64(const float* a) {
    float r[8];
#pragma unroll
    for (int j = 0; j < 8; ++j) r[j] = __fmul_rn(a[j], a[j]);
#pragma unroll
    for (int i = 8; i < 64; i += 8) {
#pragma unroll
        for (int j = 0; j < 8; ++j)
            r[j] = __fadd_rn(r[j], __fmul_rn(a[i + j], a[i + j]));
    }
    return __fadd_rn(__fadd_rn(__fadd_rn(r[0], r[1]), __fadd_rn(r[2], r[3])),
                     __fadd_rn(__fadd_rn(r[4], r[5]), __fadd_rn(r[6], r[7])));
}

// ---- kernel 1: w2[k] = np.sum(w[k]*w[k]) in numpy's order ----
__global__ void w2_kernel(const float* __restrict__ w, float* __restrict__ w2) {
    int k = blockIdx.x * blockDim.x + threadIdx.x;
    if (k < KCB) {
        float ws[64];
        const float4* wp = (const float4*)(w + (size_t)k * DDIM);
#pragma unroll
        for (int j = 0; j < 16; ++j) {
            float4 v = wp[j];
            ws[4 * j + 0] = v.x; ws[4 * j + 1] = v.y;
            ws[4 * j + 2] = v.z; ws[4 * j + 3] = v.w;
        }
        w2[k] = np_sumsq64(ws);
    }
}

// ---- kernel 2: per-row fp32-faithful argmin + gather + loss ----
__launch_bounds__(256, 2)   // allow ~256 VGPRs: xs[64] must stay resident
__global__ void vq_kernel(const float* __restrict__ x,
                          const float* __restrict__ w,
                          const float* __restrict__ w2,
                          float* __restrict__ out_idx,
                          float* __restrict__ out_q,
                          float* __restrict__ out_loss) {
    const int row = blockIdx.x * blockDim.x + threadIdx.x;

    // row into registers (SROA'd scalars; constant indices only)
    float xs[64];
    {
        const float4* xp = (const float4*)(x + (size_t)row * DDIM);
#pragma unroll
        for (int j = 0; j < 16; ++j) {
            float4 v = xp[j];
            xs[4 * j + 0] = v.x; xs[4 * j + 1] = v.y;
            xs[4 * j + 2] = v.z; xs[4 * j + 3] = v.w;
        }
    }

    // x2 in numpy's exact summation order
    const float x2 = np_sumsq64(xs);

    float best = 3.4e38f;
    int bidx = 0;

    // k-loop: 8 codewords at a time, 8 independent sequential-FMA chains.
    // Each chain is BLAS-order: m = fma(x_j, w_j, m), j ascending from 0.
#pragma clang loop unroll(disable)
    for (int k = 0; k < KCB; k += 8) {
        const float* wb = w + (size_t)k * DDIM;
        float m0 = 0.f, m1 = 0.f, m2 = 0.f, m3 = 0.f;
        float m4 = 0.f, m5 = 0.f, m6 = 0.f, m7 = 0.f;
#pragma unroll
        for (int j = 0; j < 64; j += 4) {
            float4 b0 = *(const float4*)(wb + 0 * DDIM + j);
            float4 b1 = *(const float4*)(wb + 1 * DDIM + j);
            float4 b2 = *(const float4*)(wb + 2 * DDIM + j);
            float4 b3 = *(const float4*)(wb + 3 * DDIM + j);
            float4 b4 = *(const float4*)(wb + 4 * DDIM + j);
            float4 b5 = *(const float4*)(wb + 5 * DDIM + j);
            float4 b6 = *(const float4*)(wb + 6 * DDIM + j);
            float4 b7 = *(const float4*)(wb + 7 * DDIM + j);
            float x0 = xs[j + 0], x1 = xs[j + 1], x2v = xs[j + 2], x3 = xs[j + 3];
            m0 = __fmaf_rn(x0, b0.x, m0); m0 = __fmaf_rn(x1, b0.y, m0);
            m0 = __fmaf_rn(x2v, b0.z, m0); m0 = __fmaf_rn(x3, b0.w, m0);
            m1 = __fmaf_rn(x0, b1.x, m1); m1 = __fmaf_rn(x1, b1.y, m1);
            m1 = __fmaf_rn(x2v, b1.z, m1); m1 = __fmaf_rn(x3, b1.w, m1);
            m2 = __fmaf_rn(x0, b2.x, m2); m2 = __fmaf_rn(x1, b2.y, m2);
            m2 = __fmaf_rn(x2v, b2.z, m2); m2 = __fmaf_rn(x3, b2.w, m2);
            m3 = __fmaf_rn(x0, b3.x, m3); m3 = __fmaf_rn(x1, b3.y, m3);
            m3 = __fmaf_rn(x2v, b3.z, m3); m3 = __fmaf_rn(x3, b3.w, m3);
            m4 = __fmaf_rn(x0, b4.x, m4); m4 = __fmaf_rn(x1, b4.y, m4);
            m4 = __fmaf_rn(x2v, b4.z, m4); m4 = __fmaf_rn(x3, b4.w, m4);
            m5 = __fmaf_rn(x0, b5.x, m5); m5 = __fmaf_rn(x1, b5.y, m5);
            m5 = __fmaf_rn(x2v, b5.z, m5); m5 = __fmaf_rn(x3, b5.w, m5);
            m6 = __fmaf_rn(x0, b6.x, m6); m6 = __fmaf_rn(x1, b6.y, m6);
            m6 = __fmaf_rn(x2v, b6.z, m6); m6 = __fmaf_rn(x3, b6.w, m6);
            m7 = __fmaf_rn(x0, b7.x, m7); m7 = __fmaf_rn(x1, b7.y, m7);
            m7 = __fmaf_rn(x2v, b7.z, m7); m7 = __fmaf_rn(x3, b7.w, m7);
        }
        // d2 = fl(fl(x2 - fl(2*m)) + w2[k]); ascending-k strict < tie-break
        float d0 = __fadd_rn(__fsub_rn(x2, __fmul_rn(2.0f, m0)), w2[k + 0]);
        float d1 = __fadd_rn(__fsub_rn(x2, __fmul_rn(2.0f, m1)), w2[k + 1]);
        float d2 = __fadd_rn(__fsub_rn(x2, __fmul_rn(2.0f, m2)), w2[k + 2]);
        float d3 = __fadd_rn(__fsub_rn(x2, __fmul_rn(2.0f, m3)), w2[k + 3]);
        float d4 = __fadd_rn(__fsub_rn(x2, __fmul_rn(2.0f, m4)), w2[k + 4]);
        float d5 = __fadd_rn(__fsub_rn(x2, __fmul_rn(2.0f, m5)), w2[k + 5]);
        float d6 = __fadd_rn(__fsub_rn(x2, __fmul_rn(2.0f, m6)), w2[k + 6]);
        float d7 = __fadd_rn(__fsub_rn(x2, __fmul_rn(2.0f, m7)), w2[k + 7]);
        if (d0 < best) { best = d0; bidx = k + 0; }
        if (d1 < best) { best = d1; bidx = k + 1; }
        if (d2 < best) { best = d2; bidx = k + 2; }
        if (d3 < best) { best = d3; bidx = k + 3; }
        if (d4 < best) { best = d4; bidx = k + 4; }
        if (d5 < best) { best = d5; bidx = k + 5; }
        if (d6 < best) { best = d6; bidx = k + 6; }
        if (d7 < best) { best = d7; bidx = k + 7; }
    }

    // gather winning codeword; quantized_st = fl(x + fl(q - x)); loss terms
    const float4* wq = (const float4*)(w + (size_t)bidx * DDIM);
    float4* qo = (float4*)(out_q + (size_t)row * DDIM);
    float ls = 0.0f;
#pragma unroll
    for (int j = 0; j < 16; ++j) {
        float4 wv = wq[j];
        float xv0 = xs[4 * j + 0], xv1 = xs[4 * j + 1];
        float xv2 = xs[4 * j + 2], xv3 = xs[4 * j + 3];
        float e0 = __fsub_rn(wv.x, xv0), e1 = __fsub_rn(wv.y, xv1);
        float e2 = __fsub_rn(wv.z, xv2), e3 = __fsub_rn(wv.w, xv3);
        ls = fmaf(e0, e0, ls); ls = fmaf(e1, e1, ls);
        ls = fmaf(e2, e2, ls); ls = fmaf(e3, e3, ls);
        float4 q;
        q.x = __fadd_rn(xv0, e0); q.y = __fadd_rn(xv1, e1);
        q.z = __fadd_rn(xv2, e2); q.w = __fadd_rn(xv3, e3);
        qo[j] = q;
    }
    out_idx[row] = (float)bidx;

    // loss: wave shuffle -> LDS across 4 waves -> 1 atomic per block
#pragma unroll
    for (int off = 32; off > 0; off >>= 1) ls += __shfl_down(ls, off);
    __shared__ float red[4];
    const int lane = threadIdx.x & 63;
    const int wid  = threadIdx.x >> 6;
    if (lane == 0) red[wid] = ls;
    __syncthreads();
    if (threadIdx.x == 0) {
        float t = (red[0] + red[1]) + (red[2] + red[3]);
        // vq_loss = (1 + BETA) * mean((q-x)^2), BETA=0.25
        atomicAdd(out_loss, t * (1.25f / (float)(NROWS * DDIM)));
    }
}

extern "C" void kernel_launch(void* const* d_in, const int* in_sizes, int n_in,
                              void* d_out, int out_size, void* d_ws, size_t ws_size,
                              hipStream_t stream) {
    const float* x = (const float*)d_in[0];   // encoding [N, 64]
    const float* w = (const float*)d_in[1];   // weight   [512, 64]

    float* out      = (float*)d_out;
    float* out_idx  = out;                                        // N floats
    float* out_q    = out + (size_t)NROWS;                        // N*D floats
    float* out_loss = out + (size_t)NROWS + (size_t)NROWS * DDIM; // 1 float

    float* w2 = (float*)d_ws;  // 512 floats scratch

    // loss slot must start at 0 (d_out is poisoned before each launch)
    hipMemsetAsync(out_loss, 0, sizeof(float), stream);

    w2_kernel<<<2, 256, 0, stream>>>(w, w2);
    vq_kernel<<<NROWS / 256, 256, 0, stream>>>(x, w, w2, out_idx, out_q, out_loss);
}